// Round 2
// baseline (8372.779 us; speedup 1.0000x reference)
//
#include <hip/hip_runtime.h>

#define H 128
#define NPL 100000
#define NTR 200000
#define NAR 50000
#define N_TOTAL 350000
#define OFF_TR 100000
#define OFF_AR 300000
#define EPT 500000
#define ETA 200000
#define L_LAB 100000

// ---------------- gather encode (playlists / artists) ----------------
__global__ void encode_gather_kernel(const int* __restrict__ ids,
                                     const float* __restrict__ table,
                                     const float* __restrict__ type_row,
                                     float* __restrict__ x_out, int n) {
  int t = blockIdx.x * blockDim.x + threadIdx.x;
  int i = t >> 5;
  if (i >= n) return;
  int c = (t & 31) * 4;
  float4 tv = *reinterpret_cast<const float4*>(type_row + c);
  float4 v = *reinterpret_cast<const float4*>(table + (size_t)ids[i] * H + c);
  v.x += tv.x; v.y += tv.y; v.z += tv.z; v.w += tv.w;
  *reinterpret_cast<float4*>(x_out + (size_t)i * H + c) = v;
}

// ---------------- degree ----------------
__global__ void deg_kernel(const int* __restrict__ a, const int* __restrict__ b,
                           int offA, int offB, float* __restrict__ deg, int n) {
  int e = blockIdx.x * blockDim.x + threadIdx.x;
  if (e >= n) return;
  atomicAdd(&deg[a[e] + offA], 1.0f);
  atomicAdd(&deg[b[e] + offB], 1.0f);
}

__global__ void inv_kernel(const float* __restrict__ deg, float* __restrict__ inv) {
  int i = blockIdx.x * blockDim.x + threadIdx.x;
  if (i >= N_TOTAL) return;
  inv[i] = 1.0f / fmaxf(deg[i], 1.0f);
}

// ---------------- scatter aggregation (both directions of each edge) ----------------
__global__ void scatter_kernel(const int* __restrict__ a, const int* __restrict__ b,
                               int offA, int offB, const float* __restrict__ x,
                               float* __restrict__ agg, int n) {
  int t = blockIdx.x * blockDim.x + threadIdx.x;
  int e = t >> 5;
  if (e >= n) return;
  int c = (t & 31) * 4;
  size_t ra = (size_t)(a[e] + offA) * H + c;
  size_t rb = (size_t)(b[e] + offB) * H + c;
  float4 xa = *reinterpret_cast<const float4*>(x + ra);
  float4 xb = *reinterpret_cast<const float4*>(x + rb);
  atomicAdd(&agg[rb + 0], xa.x);
  atomicAdd(&agg[rb + 1], xa.y);
  atomicAdd(&agg[rb + 2], xa.z);
  atomicAdd(&agg[rb + 3], xa.w);
  atomicAdd(&agg[ra + 0], xb.x);
  atomicAdd(&agg[ra + 1], xb.y);
  atomicAdd(&agg[ra + 2], xb.z);
  atomicAdd(&agg[ra + 3], xb.w);
}

// ---------------- encode tracks: out = track_x @ Wtr^T + btr + tt1 ----------------
__launch_bounds__(256, 2)
__global__ void encode_tr_kernel(const float* __restrict__ A,
                                 const float* __restrict__ W,
                                 const float* __restrict__ btr,
                                 const float* __restrict__ tt1,
                                 float* __restrict__ out, int M) {
  __shared__ float4 sA[8][64];
  __shared__ float4 sW[8][128];
  int m0 = blockIdx.x * 64;
  int tid = threadIdx.x;
  int cg = tid & 31, rg = tid >> 5;
  float acc[8][4];
#pragma unroll
  for (int j = 0; j < 8; j++)
#pragma unroll
    for (int i = 0; i < 4; i++) acc[j][i] = 0.f;

  for (int kc = 0; kc < 128; kc += 32) {
    __syncthreads();
    int r = tid >> 3, k4 = tid & 7;
#pragma unroll
    for (int s = 0; s < 2; s++) {
      int row = r + 32 * s;
      int gm = m0 + row; if (gm >= M) gm = M - 1;
      sA[k4][row] = *reinterpret_cast<const float4*>(A + (size_t)gm * 128 + kc + k4 * 4);
    }
#pragma unroll
    for (int s = 0; s < 4; s++) {
      int col = r + 32 * s;
      sW[k4][col] = *reinterpret_cast<const float4*>(W + (size_t)col * 128 + kc + k4 * 4);
    }
    __syncthreads();
#pragma unroll
    for (int k4i = 0; k4i < 8; k4i++) {
      float4 av[8], wv[4];
#pragma unroll
      for (int j = 0; j < 8; j++) av[j] = sA[k4i][rg + 8 * j];
#pragma unroll
      for (int i = 0; i < 4; i++) wv[i] = sW[k4i][cg + 32 * i];
#pragma unroll
      for (int j = 0; j < 8; j++)
#pragma unroll
        for (int i = 0; i < 4; i++)
          acc[j][i] += av[j].x * wv[i].x + av[j].y * wv[i].y +
                       av[j].z * wv[i].z + av[j].w * wv[i].w;
    }
  }
#pragma unroll
  for (int j = 0; j < 8; j++) {
    int gm = m0 + rg + 8 * j;
    if (gm < M) {
      float* orow = out + (size_t)gm * H;
#pragma unroll
      for (int i = 0; i < 4; i++) {
        int c = cg + 32 * i;
        orow[c] = acc[j][i] + btr[c] + tt1[c];
      }
    }
  }
}

// ---------------- SAGE layer: x = relu((agg*inv)@Wl^T + bl + x@Wr^T), in place ----------------
__launch_bounds__(256, 2)
__global__ void sage_kernel(float* __restrict__ x, const float* __restrict__ agg,
                            const float* __restrict__ inv_deg,
                            const float* __restrict__ Wl, const float* __restrict__ bl,
                            const float* __restrict__ Wr, int M) {
  __shared__ float4 sA[8][64];
  __shared__ float4 sW[8][128];
  int m0 = blockIdx.x * 64;
  int tid = threadIdx.x;
  int cg = tid & 31, rg = tid >> 5;
  float acc[8][4];
#pragma unroll
  for (int j = 0; j < 8; j++)
#pragma unroll
    for (int i = 0; i < 4; i++) acc[j][i] = 0.f;

  for (int p = 0; p < 2; p++) {
    const float* Amat = p ? x : agg;
    const float* Wmat = p ? Wr : Wl;
    for (int kc = 0; kc < 128; kc += 32) {
      __syncthreads();
      int r = tid >> 3, k4 = tid & 7;
#pragma unroll
      for (int s = 0; s < 2; s++) {
        int row = r + 32 * s;
        int gm = m0 + row; if (gm >= M) gm = M - 1;
        float4 v = *reinterpret_cast<const float4*>(Amat + (size_t)gm * H + kc + k4 * 4);
        if (p == 0) {
          float iv = inv_deg[gm];
          v.x *= iv; v.y *= iv; v.z *= iv; v.w *= iv;
        }
        sA[k4][row] = v;
      }
#pragma unroll
      for (int s = 0; s < 4; s++) {
        int col = r + 32 * s;
        sW[k4][col] = *reinterpret_cast<const float4*>(Wmat + (size_t)col * H + kc + k4 * 4);
      }
      __syncthreads();
#pragma unroll
      for (int k4i = 0; k4i < 8; k4i++) {
        float4 av[8], wv[4];
#pragma unroll
        for (int j = 0; j < 8; j++) av[j] = sA[k4i][rg + 8 * j];
#pragma unroll
        for (int i = 0; i < 4; i++) wv[i] = sW[k4i][cg + 32 * i];
#pragma unroll
        for (int j = 0; j < 8; j++)
#pragma unroll
          for (int i = 0; i < 4; i++)
            acc[j][i] += av[j].x * wv[i].x + av[j].y * wv[i].y +
                         av[j].z * wv[i].z + av[j].w * wv[i].w;
      }
    }
  }
#pragma unroll
  for (int j = 0; j < 8; j++) {
    int gm = m0 + rg + 8 * j;
    if (gm < M) {
      float* orow = x + (size_t)gm * H;
#pragma unroll
      for (int i = 0; i < 4; i++) {
        int c = cg + 32 * i;
        orow[c] = fmaxf(acc[j][i] + bl[c], 0.f);
      }
    }
  }
}

// ---------------- predictor: logits = relu([pl,tr]@Wp1^T + bp1) @ Wp2^T + bp2 ----------------
__launch_bounds__(256, 2)
__global__ void pred_kernel(const float* __restrict__ x, const int* __restrict__ lab_row,
                            const int* __restrict__ lab_col,
                            const float* __restrict__ Wp1, const float* __restrict__ bp1,
                            const float* __restrict__ Wp2, const float* __restrict__ bp2,
                            float* __restrict__ out, int M) {
  __shared__ float4 sA[8][64];
  __shared__ float4 sW[8][128];
  int m0 = blockIdx.x * 64;
  int tid = threadIdx.x;
  int cg = tid & 31, rg = tid >> 5;
  float acc[8][4];
#pragma unroll
  for (int j = 0; j < 8; j++)
#pragma unroll
    for (int i = 0; i < 4; i++) acc[j][i] = 0.f;

  for (int kc = 0; kc < 256; kc += 32) {
    __syncthreads();
    int r = tid >> 3, k4 = tid & 7;
#pragma unroll
    for (int s = 0; s < 2; s++) {
      int row = r + 32 * s;
      int gi = m0 + row; if (gi >= M) gi = M - 1;
      int srow = (kc < 128) ? lab_row[gi] : (OFF_TR + lab_col[gi]);
      sA[k4][row] = *reinterpret_cast<const float4*>(
          x + (size_t)srow * H + (kc & 127) + k4 * 4);
    }
#pragma unroll
    for (int s = 0; s < 4; s++) {
      int col = r + 32 * s;
      sW[k4][col] = *reinterpret_cast<const float4*>(Wp1 + (size_t)col * 256 + kc + k4 * 4);
    }
    __syncthreads();
#pragma unroll
    for (int k4i = 0; k4i < 8; k4i++) {
      float4 av[8], wv[4];
#pragma unroll
      for (int j = 0; j < 8; j++) av[j] = sA[k4i][rg + 8 * j];
#pragma unroll
      for (int i = 0; i < 4; i++) wv[i] = sW[k4i][cg + 32 * i];
#pragma unroll
      for (int j = 0; j < 8; j++)
#pragma unroll
        for (int i = 0; i < 4; i++)
          acc[j][i] += av[j].x * wv[i].x + av[j].y * wv[i].y +
                       av[j].z * wv[i].z + av[j].w * wv[i].w;
    }
  }
  float bp2v = bp2[0];
#pragma unroll
  for (int j = 0; j < 8; j++) {
    float s = 0.f;
#pragma unroll
    for (int i = 0; i < 4; i++) {
      int c = cg + 32 * i;
      float h = fmaxf(acc[j][i] + bp1[c], 0.f);
      s += h * Wp2[c];
    }
    s += __shfl_xor(s, 16, 32);
    s += __shfl_xor(s, 8, 32);
    s += __shfl_xor(s, 4, 32);
    s += __shfl_xor(s, 2, 32);
    s += __shfl_xor(s, 1, 32);
    if (cg == 0) {
      int gi = m0 + rg + 8 * j;
      if (gi < M) out[gi] = s + bp2v;
    }
  }
}

extern "C" void kernel_launch(void* const* d_in, const int* in_sizes, int n_in,
                              void* d_out, int out_size, void* d_ws, size_t ws_size,
                              hipStream_t stream) {
  const int*   pl_ids  = (const int*)d_in[0];
  const int*   ar_ids  = (const int*)d_in[1];
  const float* track_x = (const float*)d_in[2];
  const int*   src_pt  = (const int*)d_in[3];
  const int*   dst_pt  = (const int*)d_in[4];
  const int*   src_ta  = (const int*)d_in[5];
  const int*   dst_ta  = (const int*)d_in[6];
  const int*   lab_row = (const int*)d_in[7];
  const int*   lab_col = (const int*)d_in[8];
  const float* pl_table = (const float*)d_in[9];
  const float* ar_table = (const float*)d_in[10];
  const float* Wtr = (const float*)d_in[11];
  const float* btr = (const float*)d_in[12];
  const float* type_table = (const float*)d_in[13];
  const float* Wl0 = (const float*)d_in[14];
  const float* bl0 = (const float*)d_in[15];
  const float* Wr0 = (const float*)d_in[16];
  const float* Wl1 = (const float*)d_in[17];
  const float* bl1 = (const float*)d_in[18];
  const float* Wr1 = (const float*)d_in[19];
  const float* Wp1 = (const float*)d_in[20];
  const float* bp1 = (const float*)d_in[21];
  const float* Wp2 = (const float*)d_in[22];
  const float* bp2 = (const float*)d_in[23];
  float* out = (float*)d_out;

  float* x   = (float*)d_ws;                       // N_TOTAL*H
  float* agg = x + (size_t)N_TOTAL * H;            // N_TOTAL*H
  float* deg = agg + (size_t)N_TOTAL * H;          // N_TOTAL
  float* inv = deg + N_TOTAL;                      // N_TOTAL

  hipMemsetAsync(deg, 0, N_TOTAL * sizeof(float), stream);
  hipMemsetAsync(agg, 0, (size_t)N_TOTAL * H * sizeof(float), stream);

  // encode
  encode_gather_kernel<<<(NPL * 32 + 255) / 256, 256, 0, stream>>>(
      pl_ids, pl_table, type_table, x, NPL);
  encode_gather_kernel<<<(NAR * 32 + 255) / 256, 256, 0, stream>>>(
      ar_ids, ar_table, type_table + 2 * H, x + (size_t)OFF_AR * H, NAR);
  encode_tr_kernel<<<(NTR + 63) / 64, 256, 0, stream>>>(
      track_x, Wtr, btr, type_table + H, x + (size_t)OFF_TR * H, NTR);

  // degrees
  deg_kernel<<<(EPT + 255) / 256, 256, 0, stream>>>(src_pt, dst_pt, 0, OFF_TR, deg, EPT);
  deg_kernel<<<(ETA + 255) / 256, 256, 0, stream>>>(src_ta, dst_ta, OFF_TR, OFF_AR, deg, ETA);
  inv_kernel<<<(N_TOTAL + 255) / 256, 256, 0, stream>>>(deg, inv);

  // layer 0
  scatter_kernel<<<(EPT * 32 + 255) / 256, 256, 0, stream>>>(
      src_pt, dst_pt, 0, OFF_TR, x, agg, EPT);
  scatter_kernel<<<(ETA * 32 + 255) / 256, 256, 0, stream>>>(
      src_ta, dst_ta, OFF_TR, OFF_AR, x, agg, ETA);
  sage_kernel<<<(N_TOTAL + 63) / 64, 256, 0, stream>>>(
      x, agg, inv, Wl0, bl0, Wr0, N_TOTAL);

  // layer 1
  hipMemsetAsync(agg, 0, (size_t)N_TOTAL * H * sizeof(float), stream);
  scatter_kernel<<<(EPT * 32 + 255) / 256, 256, 0, stream>>>(
      src_pt, dst_pt, 0, OFF_TR, x, agg, EPT);
  scatter_kernel<<<(ETA * 32 + 255) / 256, 256, 0, stream>>>(
      src_ta, dst_ta, OFF_TR, OFF_AR, x, agg, ETA);
  sage_kernel<<<(N_TOTAL + 63) / 64, 256, 0, stream>>>(
      x, agg, inv, Wl1, bl1, Wr1, N_TOTAL);

  // predictor
  pred_kernel<<<(L_LAB + 63) / 64, 256, 0, stream>>>(
      x, lab_row, lab_col, Wp1, bp1, Wp2, bp2, out, L_LAB);
}

// Round 3
// 4933.820 us; speedup vs baseline: 1.6970x; 1.6970x over previous
//
#include <hip/hip_runtime.h>

#define H 128
#define NPL 100000
#define NTR 200000
#define NAR 50000
#define N_TOTAL 350000
#define OFF_TR 100000
#define OFF_AR 300000
#define EPT 500000
#define ETA 200000
#define L_LAB 100000
#define SCAN_T 1024
#define NB_SCAN ((N_TOTAL + SCAN_T - 1) / SCAN_T)   // 342

// ---------------- gather encode (playlists / artists) ----------------
__global__ void encode_gather_kernel(const int* __restrict__ ids,
                                     const float* __restrict__ table,
                                     const float* __restrict__ type_row,
                                     float* __restrict__ x_out, int n) {
  int t = blockIdx.x * blockDim.x + threadIdx.x;
  int i = t >> 5;
  if (i >= n) return;
  int c = (t & 31) * 4;
  float4 tv = *reinterpret_cast<const float4*>(type_row + c);
  float4 v = *reinterpret_cast<const float4*>(table + (size_t)ids[i] * H + c);
  v.x += tv.x; v.y += tv.y; v.z += tv.z; v.w += tv.w;
  *reinterpret_cast<float4*>(x_out + (size_t)i * H + c) = v;
}

// ---------------- CSR build ----------------
__global__ void count_kernel(const int* __restrict__ a, const int* __restrict__ b,
                             int offA, int offB, int* __restrict__ deg, int n) {
  int e = blockIdx.x * blockDim.x + threadIdx.x;
  if (e >= n) return;
  atomicAdd(&deg[a[e] + offA], 1);
  atomicAdd(&deg[b[e] + offB], 1);
}

// block-level inclusive scan; write per-element inclusive + block totals
__global__ void scan1_kernel(const int* __restrict__ deg, int* __restrict__ incl,
                             int* __restrict__ bsum) {
  __shared__ int sh[SCAN_T];
  int i = blockIdx.x * SCAN_T + threadIdx.x;
  int v = (i < N_TOTAL) ? deg[i] : 0;
  sh[threadIdx.x] = v;
  __syncthreads();
  for (int off = 1; off < SCAN_T; off <<= 1) {
    int t = (threadIdx.x >= off) ? sh[threadIdx.x - off] : 0;
    __syncthreads();
    sh[threadIdx.x] += t;
    __syncthreads();
  }
  if (i < N_TOTAL) incl[i] = sh[threadIdx.x];
  if (threadIdx.x == SCAN_T - 1) bsum[blockIdx.x] = sh[threadIdx.x];
}

// single-block exclusive scan of the 342 block totals (in place)
__global__ void scan2_kernel(int* __restrict__ bsum) {
  __shared__ int sh[512];
  int tid = threadIdx.x;
  int v = (tid < NB_SCAN) ? bsum[tid] : 0;
  sh[tid] = v;
  __syncthreads();
  for (int off = 1; off < 512; off <<= 1) {
    int t = (tid >= off) ? sh[tid - off] : 0;
    __syncthreads();
    sh[tid] += t;
    __syncthreads();
  }
  if (tid < NB_SCAN) bsum[tid] = (tid == 0) ? 0 : sh[tid - 1];
}

// finalize row_ptr (exclusive) + init cursor
__global__ void scan3_kernel(const int* __restrict__ incl, const int* __restrict__ deg,
                             const int* __restrict__ bsum, int* __restrict__ row_ptr,
                             int* __restrict__ cursor) {
  int i = blockIdx.x * blockDim.x + threadIdx.x;
  if (i >= N_TOTAL) return;
  int d = deg[i];
  int start = bsum[i >> 10] + incl[i] - d;
  row_ptr[i] = start;
  cursor[i] = start;
  if (i == N_TOTAL - 1) row_ptr[N_TOTAL] = start + d;
}

__global__ void fill_kernel(const int* __restrict__ a, const int* __restrict__ b,
                            int offA, int offB, int* __restrict__ cursor,
                            int* __restrict__ col_idx, int n) {
  int e = blockIdx.x * blockDim.x + threadIdx.x;
  if (e >= n) return;
  int u = a[e] + offA, v = b[e] + offB;
  int p = atomicAdd(&cursor[u], 1);
  col_idx[p] = v;
  int q = atomicAdd(&cursor[v], 1);
  col_idx[q] = u;
}

// ---------------- gather aggregation: agg[n] = mean of x[neighbors] ----------------
__global__ void aggregate_kernel(const float* __restrict__ x,
                                 const int* __restrict__ row_ptr,
                                 const int* __restrict__ col_idx,
                                 float* __restrict__ agg) {
  int g = (blockIdx.x * blockDim.x + threadIdx.x) >> 6;
  if (g >= N_TOTAL) return;
  int l2 = (threadIdx.x & 63) * 2;
  int s = row_ptr[g], e = row_ptr[g + 1];
  float2 acc = {0.f, 0.f};
  for (int p = s; p < e; ++p) {
    int src = col_idx[p];
    float2 v = *reinterpret_cast<const float2*>(x + (size_t)src * H + l2);
    acc.x += v.x;
    acc.y += v.y;
  }
  float inv = 1.0f / fmaxf((float)(e - s), 1.0f);
  acc.x *= inv;
  acc.y *= inv;
  *reinterpret_cast<float2*>(agg + (size_t)g * H + l2) = acc;
}

// ---------------- encode tracks: out = track_x @ Wtr^T + btr + tt1 ----------------
__launch_bounds__(256, 2)
__global__ void encode_tr_kernel(const float* __restrict__ A,
                                 const float* __restrict__ W,
                                 const float* __restrict__ btr,
                                 const float* __restrict__ tt1,
                                 float* __restrict__ out, int M) {
  __shared__ float4 sA[8][64];
  __shared__ float4 sW[8][128];
  int m0 = blockIdx.x * 64;
  int tid = threadIdx.x;
  int cg = tid & 31, rg = tid >> 5;
  float acc[8][4];
#pragma unroll
  for (int j = 0; j < 8; j++)
#pragma unroll
    for (int i = 0; i < 4; i++) acc[j][i] = 0.f;

  for (int kc = 0; kc < 128; kc += 32) {
    __syncthreads();
    int r = tid >> 3, k4 = tid & 7;
#pragma unroll
    for (int s = 0; s < 2; s++) {
      int row = r + 32 * s;
      int gm = m0 + row; if (gm >= M) gm = M - 1;
      sA[k4][row] = *reinterpret_cast<const float4*>(A + (size_t)gm * 128 + kc + k4 * 4);
    }
#pragma unroll
    for (int s = 0; s < 4; s++) {
      int col = r + 32 * s;
      sW[k4][col] = *reinterpret_cast<const float4*>(W + (size_t)col * 128 + kc + k4 * 4);
    }
    __syncthreads();
#pragma unroll
    for (int k4i = 0; k4i < 8; k4i++) {
      float4 av[8], wv[4];
#pragma unroll
      for (int j = 0; j < 8; j++) av[j] = sA[k4i][rg + 8 * j];
#pragma unroll
      for (int i = 0; i < 4; i++) wv[i] = sW[k4i][cg + 32 * i];
#pragma unroll
      for (int j = 0; j < 8; j++)
#pragma unroll
        for (int i = 0; i < 4; i++)
          acc[j][i] += av[j].x * wv[i].x + av[j].y * wv[i].y +
                       av[j].z * wv[i].z + av[j].w * wv[i].w;
    }
  }
#pragma unroll
  for (int j = 0; j < 8; j++) {
    int gm = m0 + rg + 8 * j;
    if (gm < M) {
      float* orow = out + (size_t)gm * H;
#pragma unroll
      for (int i = 0; i < 4; i++) {
        int c = cg + 32 * i;
        orow[c] = acc[j][i] + btr[c] + tt1[c];
      }
    }
  }
}

// ---------------- SAGE layer: x = relu(agg@Wl^T + bl + x@Wr^T), in place ----------------
__launch_bounds__(256, 2)
__global__ void sage_kernel(float* __restrict__ x, const float* __restrict__ agg,
                            const float* __restrict__ Wl, const float* __restrict__ bl,
                            const float* __restrict__ Wr, int M) {
  __shared__ float4 sA[8][64];
  __shared__ float4 sW[8][128];
  int m0 = blockIdx.x * 64;
  int tid = threadIdx.x;
  int cg = tid & 31, rg = tid >> 5;
  float acc[8][4];
#pragma unroll
  for (int j = 0; j < 8; j++)
#pragma unroll
    for (int i = 0; i < 4; i++) acc[j][i] = 0.f;

  for (int p = 0; p < 2; p++) {
    const float* Amat = p ? x : agg;
    const float* Wmat = p ? Wr : Wl;
    for (int kc = 0; kc < 128; kc += 32) {
      __syncthreads();
      int r = tid >> 3, k4 = tid & 7;
#pragma unroll
      for (int s = 0; s < 2; s++) {
        int row = r + 32 * s;
        int gm = m0 + row; if (gm >= M) gm = M - 1;
        sA[k4][row] = *reinterpret_cast<const float4*>(Amat + (size_t)gm * H + kc + k4 * 4);
      }
#pragma unroll
      for (int s = 0; s < 4; s++) {
        int col = r + 32 * s;
        sW[k4][col] = *reinterpret_cast<const float4*>(Wmat + (size_t)col * H + kc + k4 * 4);
      }
      __syncthreads();
#pragma unroll
      for (int k4i = 0; k4i < 8; k4i++) {
        float4 av[8], wv[4];
#pragma unroll
        for (int j = 0; j < 8; j++) av[j] = sA[k4i][rg + 8 * j];
#pragma unroll
        for (int i = 0; i < 4; i++) wv[i] = sW[k4i][cg + 32 * i];
#pragma unroll
        for (int j = 0; j < 8; j++)
#pragma unroll
          for (int i = 0; i < 4; i++)
            acc[j][i] += av[j].x * wv[i].x + av[j].y * wv[i].y +
                         av[j].z * wv[i].z + av[j].w * wv[i].w;
      }
    }
  }
#pragma unroll
  for (int j = 0; j < 8; j++) {
    int gm = m0 + rg + 8 * j;
    if (gm < M) {
      float* orow = x + (size_t)gm * H;
#pragma unroll
      for (int i = 0; i < 4; i++) {
        int c = cg + 32 * i;
        orow[c] = fmaxf(acc[j][i] + bl[c], 0.f);
      }
    }
  }
}

// ---------------- predictor: logits = relu([pl,tr]@Wp1^T + bp1) @ Wp2^T + bp2 ----------------
__launch_bounds__(256, 2)
__global__ void pred_kernel(const float* __restrict__ x, const int* __restrict__ lab_row,
                            const int* __restrict__ lab_col,
                            const float* __restrict__ Wp1, const float* __restrict__ bp1,
                            const float* __restrict__ Wp2, const float* __restrict__ bp2,
                            float* __restrict__ out, int M) {
  __shared__ float4 sA[8][64];
  __shared__ float4 sW[8][128];
  int m0 = blockIdx.x * 64;
  int tid = threadIdx.x;
  int cg = tid & 31, rg = tid >> 5;
  float acc[8][4];
#pragma unroll
  for (int j = 0; j < 8; j++)
#pragma unroll
    for (int i = 0; i < 4; i++) acc[j][i] = 0.f;

  for (int kc = 0; kc < 256; kc += 32) {
    __syncthreads();
    int r = tid >> 3, k4 = tid & 7;
#pragma unroll
    for (int s = 0; s < 2; s++) {
      int row = r + 32 * s;
      int gi = m0 + row; if (gi >= M) gi = M - 1;
      int srow = (kc < 128) ? lab_row[gi] : (OFF_TR + lab_col[gi]);
      sA[k4][row] = *reinterpret_cast<const float4*>(
          x + (size_t)srow * H + (kc & 127) + k4 * 4);
    }
#pragma unroll
    for (int s = 0; s < 4; s++) {
      int col = r + 32 * s;
      sW[k4][col] = *reinterpret_cast<const float4*>(Wp1 + (size_t)col * 256 + kc + k4 * 4);
    }
    __syncthreads();
#pragma unroll
    for (int k4i = 0; k4i < 8; k4i++) {
      float4 av[8], wv[4];
#pragma unroll
      for (int j = 0; j < 8; j++) av[j] = sA[k4i][rg + 8 * j];
#pragma unroll
      for (int i = 0; i < 4; i++) wv[i] = sW[k4i][cg + 32 * i];
#pragma unroll
      for (int j = 0; j < 8; j++)
#pragma unroll
        for (int i = 0; i < 4; i++)
          acc[j][i] += av[j].x * wv[i].x + av[j].y * wv[i].y +
                       av[j].z * wv[i].z + av[j].w * wv[i].w;
    }
  }
  float bp2v = bp2[0];
#pragma unroll
  for (int j = 0; j < 8; j++) {
    float s = 0.f;
#pragma unroll
    for (int i = 0; i < 4; i++) {
      int c = cg + 32 * i;
      float h = fmaxf(acc[j][i] + bp1[c], 0.f);
      s += h * Wp2[c];
    }
    s += __shfl_xor(s, 16, 32);
    s += __shfl_xor(s, 8, 32);
    s += __shfl_xor(s, 4, 32);
    s += __shfl_xor(s, 2, 32);
    s += __shfl_xor(s, 1, 32);
    if (cg == 0) {
      int gi = m0 + rg + 8 * j;
      if (gi < M) out[gi] = s + bp2v;
    }
  }
}

extern "C" void kernel_launch(void* const* d_in, const int* in_sizes, int n_in,
                              void* d_out, int out_size, void* d_ws, size_t ws_size,
                              hipStream_t stream) {
  const int*   pl_ids  = (const int*)d_in[0];
  const int*   ar_ids  = (const int*)d_in[1];
  const float* track_x = (const float*)d_in[2];
  const int*   src_pt  = (const int*)d_in[3];
  const int*   dst_pt  = (const int*)d_in[4];
  const int*   src_ta  = (const int*)d_in[5];
  const int*   dst_ta  = (const int*)d_in[6];
  const int*   lab_row = (const int*)d_in[7];
  const int*   lab_col = (const int*)d_in[8];
  const float* pl_table = (const float*)d_in[9];
  const float* ar_table = (const float*)d_in[10];
  const float* Wtr = (const float*)d_in[11];
  const float* btr = (const float*)d_in[12];
  const float* type_table = (const float*)d_in[13];
  const float* Wl0 = (const float*)d_in[14];
  const float* bl0 = (const float*)d_in[15];
  const float* Wr0 = (const float*)d_in[16];
  const float* Wl1 = (const float*)d_in[17];
  const float* bl1 = (const float*)d_in[18];
  const float* Wr1 = (const float*)d_in[19];
  const float* Wp1 = (const float*)d_in[20];
  const float* bp1 = (const float*)d_in[21];
  const float* Wp2 = (const float*)d_in[22];
  const float* bp2 = (const float*)d_in[23];
  float* out = (float*)d_out;

  // workspace layout
  float* x   = (float*)d_ws;                        // N_TOTAL*H floats
  float* agg = x + (size_t)N_TOTAL * H;             // N_TOTAL*H floats
  int* iws      = (int*)(agg + (size_t)N_TOTAL * H);
  int* deg      = iws;                              // N_TOTAL
  int* incl     = deg + N_TOTAL;                    // N_TOTAL
  int* row_ptr  = incl + N_TOTAL;                   // N_TOTAL+1
  int* cursor   = row_ptr + N_TOTAL + 1;            // N_TOTAL
  int* bsum     = cursor + N_TOTAL;                 // 512
  int* col_idx  = bsum + 512;                       // 2*(EPT+ETA)

  // ---- CSR build (edges are the same for both layers) ----
  hipMemsetAsync(deg, 0, N_TOTAL * sizeof(int), stream);
  count_kernel<<<(EPT + 255) / 256, 256, 0, stream>>>(src_pt, dst_pt, 0, OFF_TR, deg, EPT);
  count_kernel<<<(ETA + 255) / 256, 256, 0, stream>>>(src_ta, dst_ta, OFF_TR, OFF_AR, deg, ETA);
  scan1_kernel<<<NB_SCAN, SCAN_T, 0, stream>>>(deg, incl, bsum);
  scan2_kernel<<<1, 512, 0, stream>>>(bsum);
  scan3_kernel<<<(N_TOTAL + 255) / 256, 256, 0, stream>>>(incl, deg, bsum, row_ptr, cursor);
  fill_kernel<<<(EPT + 255) / 256, 256, 0, stream>>>(src_pt, dst_pt, 0, OFF_TR, cursor, col_idx, EPT);
  fill_kernel<<<(ETA + 255) / 256, 256, 0, stream>>>(src_ta, dst_ta, OFF_TR, OFF_AR, cursor, col_idx, ETA);

  // ---- encode ----
  encode_gather_kernel<<<(NPL * 32 + 255) / 256, 256, 0, stream>>>(
      pl_ids, pl_table, type_table, x, NPL);
  encode_gather_kernel<<<(NAR * 32 + 255) / 256, 256, 0, stream>>>(
      ar_ids, ar_table, type_table + 2 * H, x + (size_t)OFF_AR * H, NAR);
  encode_tr_kernel<<<(NTR + 63) / 64, 256, 0, stream>>>(
      track_x, Wtr, btr, type_table + H, x + (size_t)OFF_TR * H, NTR);

  // ---- layer 0 ----
  aggregate_kernel<<<(N_TOTAL * 64 + 255) / 256, 256, 0, stream>>>(x, row_ptr, col_idx, agg);
  sage_kernel<<<(N_TOTAL + 63) / 64, 256, 0, stream>>>(x, agg, Wl0, bl0, Wr0, N_TOTAL);

  // ---- layer 1 ----
  aggregate_kernel<<<(N_TOTAL * 64 + 255) / 256, 256, 0, stream>>>(x, row_ptr, col_idx, agg);
  sage_kernel<<<(N_TOTAL + 63) / 64, 256, 0, stream>>>(x, agg, Wl1, bl1, Wr1, N_TOTAL);

  // ---- predictor ----
  pred_kernel<<<(L_LAB + 63) / 64, 256, 0, stream>>>(
      x, lab_row, lab_col, Wp1, bp1, Wp2, bp2, out, L_LAB);
}